// Round 15
// baseline (724.107 us; speedup 1.0000x reference)
//
#include <hip/hip_runtime.h>

#define IN_F 4096
#define OUT_F 11008
#define NGROUPS 32
#define M_TOTAL 8192
#define BM 256
#define BN 256
#define BK 32
#define NKT (IN_F / BK)  // 128 K-tiles = 128 phases

typedef _Float16 half_t;  // LDS element size only; payload is bf16 bits
typedef unsigned short ushort_t;
typedef __attribute__((ext_vector_type(8))) short short8;   // bf16x8 frag (4 VGPR)
typedef __attribute__((ext_vector_type(4))) float f32x4;
typedef __attribute__((ext_vector_type(4))) int i32x4;
typedef __attribute__((ext_vector_type(4))) unsigned short us4;

typedef __attribute__((address_space(1))) const void gvoid_t;
typedef __attribute__((address_space(3))) void lvoid_t;

__device__ __forceinline__ unsigned short f32_to_bf16_rne(float f) {
  unsigned int u = __builtin_bit_cast(unsigned int, f);
  u += 0x7FFFu + ((u >> 16) & 1u);
  return (unsigned short)(u >> 16);
}

// ---------------- prepass 1: x fp32 -> bf16 (RNE) ----------------
__global__ void convert_x_k(const float* __restrict__ x, ushort_t* __restrict__ xh) {
  const int n4 = M_TOTAL * IN_F / 4;
  int stride = gridDim.x * blockDim.x;
  for (int i = blockIdx.x * blockDim.x + threadIdx.x; i < n4; i += stride) {
    f32x4 v = __builtin_nontemporal_load((const f32x4*)x + i);
    us4 h;
    h[0] = f32_to_bf16_rne(v[0]);
    h[1] = f32_to_bf16_rne(v[1]);
    h[2] = f32_to_bf16_rne(v[2]);
    h[3] = f32_to_bf16_rne(v[3]);
    ((us4*)xh)[i] = h;
  }
}

// ---------------- prepass 2: W (int32-materialized int8) * group scale -> bf16 ----------
__global__ void dequant_w_k(const int* __restrict__ wq,
                            const float* __restrict__ scales,
                            ushort_t* __restrict__ wh) {
  int row = blockIdx.x;
  int t = threadIdx.x;  // 512 threads, 8 weights each
  size_t base = (size_t)row * IN_F + (size_t)t * 8;
  float s = scales[row * NGROUPS + (t >> 4)];
  i32x4 q0 = __builtin_nontemporal_load((const i32x4*)(wq + base));
  i32x4 q1 = __builtin_nontemporal_load((const i32x4*)(wq + base) + 1);
  us4 h0, h1;
#pragma unroll
  for (int j = 0; j < 4; ++j) h0[j] = f32_to_bf16_rne((float)q0[j] * s);
#pragma unroll
  for (int j = 0; j < 4; ++j) h1[j] = f32_to_bf16_rne((float)q1[j] * s);
  *(us4*)(wh + base) = h0;
  *(us4*)(wh + base + 4) = h1;
}

// ------- 256x256 GEMM, BK=32, 4-slot rotation, CROSS-PHASE READ-AHEAD -------
// Phase t: [rd tile t+1 -> next reg set][stage tile t+3][LGKM(12): drains PREV
// phase's reads only][32 MFMA on CURRENT set][VMCNT(4)][BAR]. MFMA is gated on
// reads issued one full phase earlier => tile t+1's reads drain UNDER tile t's
// MFMA burst (LDS pipe || MFMA pipe instead of serial sum).
// Ledger: read slot (t+1)&3; stage slot (t+3)&3 (last read at t-2, drained by
// lgkm in t-1 + end-of-(t-1) barrier); in-flight gload slots {(t+2),(t+3)}&3
// disjoint from read slot; VMCNT(4) at end of t retires tile t+2 (read at t+1).
// LDS [slot][op][256x32] bf16, 64 B rows, swizzle c ^= (row&6)<<3 (both sides).
// K-accumulation order identical to r13/r14 => same numerics.

#define BAR() __builtin_amdgcn_s_barrier()
#define SB0() __builtin_amdgcn_sched_barrier(0)
#define PRIO1() __builtin_amdgcn_s_setprio(1)
#define PRIO0() __builtin_amdgcn_s_setprio(0)
#define VMCNT(N) asm volatile("s_waitcnt vmcnt(" #N ")" ::: "memory")
#define LGKM(N) asm volatile("s_waitcnt lgkmcnt(" #N ")" ::: "memory")

#define GLD(G, D) __builtin_amdgcn_global_load_lds((gvoid_t*)(G), (lvoid_t*)(D), 16, 0, 0)

// Stage tile KT -> slot S: A 2 rounds + B 2 rounds, 4 loads/thread (16 KB x2)
#define STAGE(KT, S)                                                       \
  do {                                                                     \
    const half_t* gA_ = pAsrc + (KT) * 32;                                 \
    const half_t* gB_ = pBsrc + (KT) * 32;                                 \
    char* dA_ = (char*)&lds[S][0][0] + t16;                                \
    char* dB_ = (char*)&lds[S][1][0] + t16;                                \
    GLD(gA_, dA_);                                                         \
    GLD(gA_ + 128 * IN_F, dA_ + 8192);                                     \
    GLD(gB_, dB_);                                                         \
    GLD(gB_ + 128 * IN_F, dB_ + 8192);                                     \
  } while (0)

// 12 ds_read_b128: 8 A-frags + 4 B-frags of slot S into reg sets AA/BB
#define RDS(AA, BB, S)                                                     \
  do {                                                                     \
    const char* Ab_ = (const char*)&lds[S][0][0];                          \
    const char* Bb_ = (const char*)&lds[S][1][0];                          \
    _Pragma("unroll") for (int m_ = 0; m_ < 8; ++m_)                       \
        AA[m_] = *(const short8*)(Ab_ + aoff + m_ * 1024);                 \
    _Pragma("unroll") for (int n_ = 0; n_ < 4; ++n_)                       \
        BB[n_] = *(const short8*)(Bb_ + boff + n_ * 1024);                 \
  } while (0)

#define MFMA_ALL(AA, BB)                                                   \
  do {                                                                     \
    _Pragma("unroll") for (int m_ = 0; m_ < 8; ++m_)                       \
        _Pragma("unroll") for (int n_ = 0; n_ < 4; ++n_)                   \
            acc[m_][n_] = __builtin_amdgcn_mfma_f32_16x16x32_bf16(         \
                AA[m_], BB[n_], acc[m_][n_], 0, 0, 0);                     \
  } while (0)

// Phase with stage. FEN: 4 = vmcnt(4)
#define PH(RA_, RB_, RSLOT, STKT, SSLOT, MA_, MB_, FEN)                    \
  do {                                                                     \
    RDS(RA_, RB_, RSLOT);                                                  \
    STAGE(STKT, SSLOT);                                                    \
    LGKM(12); SB0(); PRIO1();                                              \
    MFMA_ALL(MA_, MB_);                                                    \
    PRIO0();                                                               \
    if ((FEN) == 4) VMCNT(4);                                              \
    BAR(); SB0();                                                          \
  } while (0)

// Phase without stage (tail). FEN: 0 = vmcnt(0), -1 = none
#define PHN(RA_, RB_, RSLOT, MA_, MB_, FEN)                                \
  do {                                                                     \
    RDS(RA_, RB_, RSLOT);                                                  \
    LGKM(12); SB0(); PRIO1();                                              \
    MFMA_ALL(MA_, MB_);                                                    \
    PRIO0();                                                               \
    if ((FEN) == 0) VMCNT(0);                                              \
    BAR(); SB0();                                                          \
  } while (0)

__global__ __launch_bounds__(512, 1) void gemm_k(const half_t* __restrict__ A,
                                                 const half_t* __restrict__ B,
                                                 const float* __restrict__ bias,
                                                 float* __restrict__ C) {
  __shared__ __align__(16) half_t lds[4][2][8192];  // 4 slots x (A 16K + B 16K) = 128 KiB

  const int tid = threadIdx.x;
  const int lane = tid & 63;
  const int wv = tid >> 6;
  const int wm = wv >> 2;    // 2 wave-rows (128 rows)
  const int wn = wv & 3;     // 4 wave-cols (64 cols)
  const int t16 = tid * 16;  // linear stage dest byte within a 16 KB region

  // Band-rasterized, XCD-aware map (nwg = 1376 = 8*172, bijective):
  const int nwg = gridDim.x;
  const int perx = nwg >> 3;  // 172
  const int L = ((int)blockIdx.x & 7) * perx + ((int)blockIdx.x >> 3);
  const int band = L >> 7;
  const int rr_ = L & 127;
  const int bn0 = band << 2;
  const int cols = (43 - bn0) < 4 ? (43 - bn0) : 4;
  const int bm = rr_ / cols;
  const int bn = bn0 + rr_ % cols;
  const int row0 = bm * BM;
  const int col0 = bn * BN;

  // staging source (pre-swizzled; involution c ^= (row&6)<<3)
  const int c16 = (tid & 3) * 16;
  const int srow = tid >> 2;  // 0..127; +128 round preserves row&6
  const int clog = c16 ^ ((srow & 6) << 3);
  const int kidx = clog >> 1;
  const half_t* pAsrc = A + (size_t)(row0 + srow) * IN_F + kidx;
  const half_t* pBsrc = B + (size_t)(col0 + srow) * IN_F + kidx;

  // fragment read offsets (swizzled); frag stride 16 rows * 64 B = 1024
  const int r16 = lane & 15;
  const int kg = lane >> 4;
  const int aoff = (wm * 128 + r16) * 64 + ((kg * 16) ^ ((r16 & 6) << 3));
  const int boff = (wn * 64 + r16) * 64 + ((kg * 16) ^ ((r16 & 6) << 3));

  f32x4 acc[8][4];
#pragma unroll
  for (int m = 0; m < 8; ++m)
#pragma unroll
    for (int n = 0; n < 4; ++n) acc[m][n] = (f32x4){0.f, 0.f, 0.f, 0.f};

  short8 aA[8], bA[4], aB[8], bB[4];  // double-buffered fragment sets

  // prologue: stage tiles 0,1,2 -> slots 0,1,2; vmcnt(4): tiles 0,1 landed
  STAGE(0, 0);
  STAGE(1, 1);
  STAGE(2, 2);
  VMCNT(4);
  BAR();
  SB0();
  RDS(aA, bA, 0);  // tile 0 -> A set (tile t lives in A set iff t even)

  for (int u = 0; u < 62; ++u) {
    const int t0 = 2 * u;
    PH(aB, bB, (t0 + 1) & 3, t0 + 3, (t0 + 3) & 3, aA, bA, 4);  // phase t0
    PH(aA, bA, (t0 + 2) & 3, t0 + 4, (t0 + 4) & 3, aB, bB, 4);  // phase t0+1
  }
  PH(aB, bB, 1, 127, 3, aA, bA, 4);  // t=124: rd 125, stage 127; retire 126
  PHN(aA, bA, 2, aB, bB, 0);         // t=125: rd 126; vmcnt(0) retires 127
  PHN(aB, bB, 3, aA, bA, -1);        // t=126: rd 127
  LGKM(0);
  SB0();
  MFMA_ALL(aB, bB);                  // t=127

  // epilogue: fp16 rounding + fp16 bias add (reference numerics), NT fp32 store
  const int kg4 = kg * 4;
#pragma unroll
  for (int nf = 0; nf < 4; ++nf) {
    int col = col0 + wn * 64 + nf * 16 + r16;
    _Float16 bh = (_Float16)bias[col];
#pragma unroll
    for (int mf = 0; mf < 8; ++mf) {
      int rb = row0 + wm * 128 + mf * 16 + kg4;
#pragma unroll
      for (int r = 0; r < 4; ++r) {
        _Float16 v = (_Float16)acc[mf][nf][r] + bh;
        __builtin_nontemporal_store((float)v, &C[(size_t)(rb + r) * OUT_F + col]);
      }
    }
  }
}

// ---------------- emergency fallback (ws too small) ----------------
__global__ void naive_k(const float* __restrict__ x, const int* __restrict__ wq,
                        const float* __restrict__ scales, const float* __restrict__ bias,
                        float* __restrict__ out) {
  long idx = (long)blockIdx.x * blockDim.x + threadIdx.x;
  if (idx >= (long)M_TOTAL * OUT_F) return;
  int m = (int)(idx / OUT_F);
  int n = (int)(idx % OUT_F);
  float acc = 0.f;
  for (int g = 0; g < NGROUPS; ++g) {
    float s = scales[n * NGROUPS + g];
    for (int k = g * 128; k < (g + 1) * 128; ++k) {
      _Float16 xv = (_Float16)x[(size_t)m * IN_F + k];
      _Float16 wv = (_Float16)((float)wq[(size_t)n * IN_F + k] * s);
      acc += (float)xv * (float)wv;
    }
  }
  _Float16 r = (_Float16)acc + (_Float16)bias[n];
  out[idx] = (float)r;
}

extern "C" void kernel_launch(void* const* d_in, const int* in_sizes, int n_in,
                              void* d_out, int out_size, void* d_ws, size_t ws_size,
                              hipStream_t stream) {
  const float* x = (const float*)d_in[0];
  const int* wq = (const int*)d_in[1];
  const float* scales = (const float*)d_in[2];
  const float* bias = (const float*)d_in[3];
  float* out = (float*)d_out;

  const size_t xh_bytes = (size_t)M_TOTAL * IN_F * 2;
  const size_t wh_bytes = (size_t)OUT_F * IN_F * 2;

  if (ws_size >= xh_bytes + wh_bytes) {
    ushort_t* xh = (ushort_t*)d_ws;
    ushort_t* wh = (ushort_t*)((char*)d_ws + xh_bytes);
    convert_x_k<<<2048, 256, 0, stream>>>(x, xh);
    dequant_w_k<<<OUT_F, 512, 0, stream>>>(wq, scales, wh);
    gemm_k<<<(M_TOTAL / BM) * (OUT_F / BN), 512, 0, stream>>>(
        (const half_t*)xh, (const half_t*)wh, bias, out);
  } else {
    long total = (long)M_TOTAL * OUT_F;
    naive_k<<<(int)((total + 255) / 256), 256, 0, stream>>>(x, wq, scales, bias, out);
  }
}

// Round 16
// 718.247 us; speedup vs baseline: 1.0082x; 1.0082x over previous
//
#include <hip/hip_runtime.h>

#define IN_F 4096
#define OUT_F 11008
#define NGROUPS 32
#define M_TOTAL 8192
#define BM 256
#define BN 256
#define BK 32
#define NKT (IN_F / BK)  // 128 K-tiles = 128 phases

typedef _Float16 half_t;  // LDS element size only; payload is bf16 bits
typedef unsigned short ushort_t;
typedef __attribute__((ext_vector_type(8))) short short8;   // bf16x8 frag (4 VGPR)
typedef __attribute__((ext_vector_type(4))) float f32x4;
typedef __attribute__((ext_vector_type(4))) int i32x4;
typedef __attribute__((ext_vector_type(4))) unsigned short us4;

typedef __attribute__((address_space(1))) const void gvoid_t;
typedef __attribute__((address_space(3))) void lvoid_t;

__device__ __forceinline__ unsigned short f32_to_bf16_rne(float f) {
  unsigned int u = __builtin_bit_cast(unsigned int, f);
  u += 0x7FFFu + ((u >> 16) & 1u);
  return (unsigned short)(u >> 16);
}

// ---------------- prepass 1: x fp32 -> bf16 (RNE) ----------------
__global__ void convert_x_k(const float* __restrict__ x, ushort_t* __restrict__ xh) {
  const int n4 = M_TOTAL * IN_F / 4;
  int stride = gridDim.x * blockDim.x;
  for (int i = blockIdx.x * blockDim.x + threadIdx.x; i < n4; i += stride) {
    f32x4 v = __builtin_nontemporal_load((const f32x4*)x + i);
    us4 h;
    h[0] = f32_to_bf16_rne(v[0]);
    h[1] = f32_to_bf16_rne(v[1]);
    h[2] = f32_to_bf16_rne(v[2]);
    h[3] = f32_to_bf16_rne(v[3]);
    ((us4*)xh)[i] = h;
  }
}

// ---------------- prepass 2: W (int32-materialized int8) * group scale -> bf16 ----------
__global__ void dequant_w_k(const int* __restrict__ wq,
                            const float* __restrict__ scales,
                            ushort_t* __restrict__ wh) {
  int row = blockIdx.x;
  int t = threadIdx.x;  // 512 threads, 8 weights each
  size_t base = (size_t)row * IN_F + (size_t)t * 8;
  float s = scales[row * NGROUPS + (t >> 4)];
  i32x4 q0 = __builtin_nontemporal_load((const i32x4*)(wq + base));
  i32x4 q1 = __builtin_nontemporal_load((const i32x4*)(wq + base) + 1);
  us4 h0, h1;
#pragma unroll
  for (int j = 0; j < 4; ++j) h0[j] = f32_to_bf16_rne((float)q0[j] * s);
#pragma unroll
  for (int j = 0; j < 4; ++j) h1[j] = f32_to_bf16_rne((float)q1[j] * s);
  *(us4*)(wh + base) = h0;
  *(us4*)(wh + base + 4) = h1;
}

// --- 256x256 GEMM, BK=32, 4-slot rotation, ANTI-PHASE WAVE GROUPS ---
// SIMD = wv&3: each SIMD hosts one group-0 wave (wv<4) and one group-1 wave (wv>=4).
// G0 phase t: [rd t+1][stage t+3][lgkm(12): drains t-1 reads][MFMA t][vmcnt(4)][bar]
// G1 phase t: [lgkm(0): drains its late t-1 reads][MFMA t][rd t+1][stage t+3][vmcnt(4)][bar]
// => at barrier release G1's MFMA runs while G0's reads drain; roles swap mid-phase;
// the SIMD matrix pipe is fed through the read windows (the anti-phase that
// identically-ordered waves can never reach: r7-r15 all nulls at ~50% duty).
// Ledger (both orders): every read of tile t-1 is lgkm-drained by its own wave before
// the end-of-(t-1) barrier => stage at t targets a fully-read region; each wave passes
// vmcnt(4) before its barrier => tile staged at t-1 (read at t+1) visible at release.
// Barrier count identical in both branches. LDS [slot][op][256x32] bf16, swizzle
// c ^= (row&6)<<3 both sides. K-order identical to r13-r15 => same numerics.

#define BAR() __builtin_amdgcn_s_barrier()
#define SB0() __builtin_amdgcn_sched_barrier(0)
#define PRIO1() __builtin_amdgcn_s_setprio(1)
#define PRIO0() __builtin_amdgcn_s_setprio(0)
#define VMCNT(N) asm volatile("s_waitcnt vmcnt(" #N ")" ::: "memory")
#define LGKM(N) asm volatile("s_waitcnt lgkmcnt(" #N ")" ::: "memory")

#define GLD(G, D) __builtin_amdgcn_global_load_lds((gvoid_t*)(G), (lvoid_t*)(D), 16, 0, 0)

#define STAGE(KT, S)                                                       \
  do {                                                                     \
    const half_t* gA_ = pAsrc + (KT) * 32;                                 \
    const half_t* gB_ = pBsrc + (KT) * 32;                                 \
    char* dA_ = (char*)&lds[S][0][0] + t16;                                \
    char* dB_ = (char*)&lds[S][1][0] + t16;                                \
    GLD(gA_, dA_);                                                         \
    GLD(gA_ + 128 * IN_F, dA_ + 8192);                                     \
    GLD(gB_, dB_);                                                         \
    GLD(gB_ + 128 * IN_F, dB_ + 8192);                                     \
  } while (0)

#define RDS(AA, BB, S)                                                     \
  do {                                                                     \
    const char* Ab_ = (const char*)&lds[S][0][0];                          \
    const char* Bb_ = (const char*)&lds[S][1][0];                          \
    _Pragma("unroll") for (int m_ = 0; m_ < 8; ++m_)                       \
        AA[m_] = *(const short8*)(Ab_ + aoff + m_ * 1024);                 \
    _Pragma("unroll") for (int n_ = 0; n_ < 4; ++n_)                       \
        BB[n_] = *(const short8*)(Bb_ + boff + n_ * 1024);                 \
  } while (0)

#define MFMA_ALL(AA, BB)                                                   \
  do {                                                                     \
    _Pragma("unroll") for (int m_ = 0; m_ < 8; ++m_)                       \
        _Pragma("unroll") for (int n_ = 0; n_ < 4; ++n_)                   \
            acc[m_][n_] = __builtin_amdgcn_mfma_f32_16x16x32_bf16(         \
                AA[m_], BB[n_], acc[m_][n_], 0, 0, 0);                     \
  } while (0)

// Group 0 phase: reads first, MFMA gated on last phase's reads via counted lgkm
#define PH0(RA_, RB_, RSLOT, STKT, SSLOT, MA_, MB_)                        \
  do {                                                                     \
    RDS(RA_, RB_, RSLOT);                                                  \
    STAGE(STKT, SSLOT);                                                    \
    LGKM(12); SB0(); PRIO1();                                              \
    MFMA_ALL(MA_, MB_);                                                    \
    PRIO0(); VMCNT(4); BAR(); SB0();                                       \
  } while (0)

// Group 1 phase: MFMA first (its reads were issued late last phase), reads after
#define PH1(RA_, RB_, RSLOT, STKT, SSLOT, MA_, MB_)                        \
  do {                                                                     \
    LGKM(0); SB0(); PRIO1();                                               \
    MFMA_ALL(MA_, MB_);                                                    \
    PRIO0();                                                               \
    RDS(RA_, RB_, RSLOT);                                                  \
    STAGE(STKT, SSLOT);                                                    \
    VMCNT(4); BAR(); SB0();                                                \
  } while (0)

__global__ __launch_bounds__(512, 1) void gemm_k(const half_t* __restrict__ A,
                                                 const half_t* __restrict__ B,
                                                 const float* __restrict__ bias,
                                                 float* __restrict__ C) {
  __shared__ __align__(16) half_t lds[4][2][8192];  // 4 slots x (A 16K + B 16K) = 128 KiB

  const int tid = threadIdx.x;
  const int lane = tid & 63;
  const int wv = tid >> 6;
  const int wm = wv >> 2;    // 2 wave-rows (128 rows)  [also = group id]
  const int wn = wv & 3;     // 4 wave-cols (64 cols)
  const int t16 = tid * 16;  // linear stage dest byte within a 16 KB region

  // Band-rasterized, XCD-aware map (nwg = 1376 = 8*172, bijective):
  const int nwg = gridDim.x;
  const int perx = nwg >> 3;  // 172
  const int L = ((int)blockIdx.x & 7) * perx + ((int)blockIdx.x >> 3);
  const int band = L >> 7;
  const int rr_ = L & 127;
  const int bn0 = band << 2;
  const int cols = (43 - bn0) < 4 ? (43 - bn0) : 4;
  const int bm = rr_ / cols;
  const int bn = bn0 + rr_ % cols;
  const int row0 = bm * BM;
  const int col0 = bn * BN;

  // staging source (pre-swizzled; involution c ^= (row&6)<<3)
  const int c16 = (tid & 3) * 16;
  const int srow = tid >> 2;
  const int clog = c16 ^ ((srow & 6) << 3);
  const int kidx = clog >> 1;
  const half_t* pAsrc = A + (size_t)(row0 + srow) * IN_F + kidx;
  const half_t* pBsrc = B + (size_t)(col0 + srow) * IN_F + kidx;

  // fragment read offsets (swizzled); frag stride 16 rows * 64 B = 1024
  const int r16 = lane & 15;
  const int kg = lane >> 4;
  const int aoff = (wm * 128 + r16) * 64 + ((kg * 16) ^ ((r16 & 6) << 3));
  const int boff = (wn * 64 + r16) * 64 + ((kg * 16) ^ ((r16 & 6) << 3));

  f32x4 acc[8][4];
#pragma unroll
  for (int m = 0; m < 8; ++m)
#pragma unroll
    for (int n = 0; n < 4; ++n) acc[m][n] = (f32x4){0.f, 0.f, 0.f, 0.f};

  short8 aA[8], bA[4], aB[8], bB[4];  // double-buffered fragment sets (tile t in set t&1)

  // prologue: stage tiles 0,1,2 -> slots 0,1,2; vmcnt(4): tiles 0,1 landed
  STAGE(0, 0);
  STAGE(1, 1);
  STAGE(2, 2);
  VMCNT(4);
  BAR();
  SB0();
  RDS(aA, bA, 0);  // tile 0 for phase 0's MFMA

  if (wv < 4) {  // ---------------- group 0 ----------------
    for (int u = 0; u < 62; ++u) {
      const int t0 = 2 * u;
      PH0(aB, bB, (t0 + 1) & 3, t0 + 3, (t0 + 3) & 3, aA, bA);  // phase t0
      PH0(aA, bA, (t0 + 2) & 3, t0 + 4, (t0 + 4) & 3, aB, bB);  // phase t0+1
    }
    // t=124: rd 125, stage 127->slot3; retire 126
    PH0(aB, bB, 1, 127, 3, aA, bA);
    // t=125: rd 126; vmcnt(0) -> tile 127 resident
    RDS(aA, bA, 2);
    LGKM(12); SB0(); PRIO1(); MFMA_ALL(aB, bB); PRIO0();
    VMCNT(0); BAR(); SB0();
    // t=126: rd 127
    RDS(aB, bB, 3);
    LGKM(12); SB0(); PRIO1(); MFMA_ALL(aA, bA); PRIO0();
    BAR(); SB0();
    // t=127
    LGKM(0); SB0();
    MFMA_ALL(aB, bB);
  } else {  // ---------------- group 1 (MFMA-first) ----------------
    for (int u = 0; u < 62; ++u) {
      const int t0 = 2 * u;
      PH1(aB, bB, (t0 + 1) & 3, t0 + 3, (t0 + 3) & 3, aA, bA);  // phase t0
      PH1(aA, bA, (t0 + 2) & 3, t0 + 4, (t0 + 4) & 3, aB, bB);  // phase t0+1
    }
    // t=124
    PH1(aB, bB, 1, 127, 3, aA, bA);
    // t=125
    LGKM(0); SB0(); PRIO1(); MFMA_ALL(aB, bB); PRIO0();
    RDS(aA, bA, 2);
    VMCNT(0); BAR(); SB0();
    // t=126
    LGKM(0); SB0(); PRIO1(); MFMA_ALL(aA, bA); PRIO0();
    RDS(aB, bB, 3);
    BAR(); SB0();
    // t=127
    LGKM(0); SB0();
    MFMA_ALL(aB, bB);
  }

  // epilogue: fp16 rounding + fp16 bias add (reference numerics), NT fp32 store
  const int kg4 = kg * 4;
#pragma unroll
  for (int nf = 0; nf < 4; ++nf) {
    int col = col0 + wn * 64 + nf * 16 + r16;
    _Float16 bh = (_Float16)bias[col];
#pragma unroll
    for (int mf = 0; mf < 8; ++mf) {
      int rb = row0 + wm * 128 + mf * 16 + kg4;
#pragma unroll
      for (int r = 0; r < 4; ++r) {
        _Float16 v = (_Float16)acc[mf][nf][r] + bh;
        __builtin_nontemporal_store((float)v, &C[(size_t)(rb + r) * OUT_F + col]);
      }
    }
  }
}

// ---------------- emergency fallback (ws too small) ----------------
__global__ void naive_k(const float* __restrict__ x, const int* __restrict__ wq,
                        const float* __restrict__ scales, const float* __restrict__ bias,
                        float* __restrict__ out) {
  long idx = (long)blockIdx.x * blockDim.x + threadIdx.x;
  if (idx >= (long)M_TOTAL * OUT_F) return;
  int m = (int)(idx / OUT_F);
  int n = (int)(idx % OUT_F);
  float acc = 0.f;
  for (int g = 0; g < NGROUPS; ++g) {
    float s = scales[n * NGROUPS + g];
    for (int k = g * 128; k < (g + 1) * 128; ++k) {
      _Float16 xv = (_Float16)x[(size_t)m * IN_F + k];
      _Float16 wv = (_Float16)((float)wq[(size_t)n * IN_F + k] * s);
      acc += (float)xv * (float)wv;
    }
  }
  _Float16 r = (_Float16)acc + (_Float16)bias[n];
  out[idx] = (float)r;
}

extern "C" void kernel_launch(void* const* d_in, const int* in_sizes, int n_in,
                              void* d_out, int out_size, void* d_ws, size_t ws_size,
                              hipStream_t stream) {
  const float* x = (const float*)d_in[0];
  const int* wq = (const int*)d_in[1];
  const float* scales = (const float*)d_in[2];
  const float* bias = (const float*)d_in[3];
  float* out = (float*)d_out;

  const size_t xh_bytes = (size_t)M_TOTAL * IN_F * 2;
  const size_t wh_bytes = (size_t)OUT_F * IN_F * 2;

  if (ws_size >= xh_bytes + wh_bytes) {
    ushort_t* xh = (ushort_t*)d_ws;
    ushort_t* wh = (ushort_t*)((char*)d_ws + xh_bytes);
    convert_x_k<<<2048, 256, 0, stream>>>(x, xh);
    dequant_w_k<<<OUT_F, 512, 0, stream>>>(wq, scales, wh);
    gemm_k<<<(M_TOTAL / BM) * (OUT_F / BN), 512, 0, stream>>>(
        (const half_t*)xh, (const half_t*)wh, bias, out);
  } else {
    long total = (long)M_TOTAL * OUT_F;
    naive_k<<<(int)((total + 255) / 256), 256, 0, stream>>>(x, wq, scales, bias, out);
  }
}